// Round 3
// baseline (5445.017 us; speedup 1.0000x reference)
//
#include <hip/hip_runtime.h>
#include <hip/hip_bf16.h>
#include <stdint.h>

// Problem constants
#define B_    8
#define CIN   64
#define COUT  64
#define HW_   256
#define KS    31
#define PADDED 287   // padded spatial dim for P (pad offset 15): x' = x+15, x' in [0,287)
#define CG    8      // channels per group
#define NG    8      // number of channel groups (CIN/CG)
#define TY    16     // output tile rows per block
#define TX    32     // output tile cols per block
#define PR    48     // staged patch rows (16+31-1=46 real, +2 slack)
#define PC    64     // staged patch cols (32+31-1=62 real, +2 slack)
#define UPAD  32     // u-taps padded 31->32 (u=31 weights are zero)
#define VP    16     // v-pair count: v = vp*2+dv, dv in {0,1}; v==31 zero-padded
#define NSTEP (VP * UPAD)  // 512 K-steps of K=16 per channel-group

typedef __attribute__((ext_vector_type(8))) short short8;
typedef __attribute__((ext_vector_type(16))) float f32x16;

__device__ __forceinline__ short f2bf(float f) {
    __hip_bfloat16 h = __float2bfloat16(f);
    return __builtin_bit_cast(short, h);
}

// P layout: [b][g][y'][x'][cc] bf16, y',x' in [0,287), value = signal[b][g*8+cc][y'-15][x'-15] or 0
__global__ void pad_input_kernel(const float* __restrict__ sig, short* __restrict__ P) {
    int idx = blockIdx.x * 256 + threadIdx.x;   // total 8*8*287*287 = 5,271,616
    if (idx >= B_ * NG * PADDED * PADDED) return;
    int x = idx % PADDED;
    int t = idx / PADDED;
    int y = t % PADDED;
    t /= PADDED;
    int g = t % NG;
    int b = t / NG;
    int ys = y - 15, xs = x - 15;
    bool in = (ys >= 0 && ys < HW_ && xs >= 0 && xs < HW_);
    const float* sp = sig + (((size_t)(b*CIN + g*CG) * HW_ + ys) * HW_ + xs);
    short8 v;
#pragma unroll
    for (int cc = 0; cc < CG; ++cc) {
        float f = in ? sp[(size_t)cc * HW_ * HW_] : 0.0f;
        v[cc] = f2bf(f);
    }
    *reinterpret_cast<short8*>(P + (size_t)idx * CG) = v;
}

// Wp layout (32x32x16 MFMA): [g][vp][u(32)][mt(2)][o'(32)][k(16)]
// k = dv*8 + cc, v = vp*2 + dv (v==31 zero-padded), u==31 zero-padded, o = mt*32 + o'
// A-frag lane mapping: row(o') = lane&31, k-base = (lane>>5)*8, 8 contiguous shorts (16 B)
// Linear in step s = vp*32 + u  ->  A prefetch address is Wg + s*1024.
__global__ void pack_weight_kernel(const float* __restrict__ w, short* __restrict__ Wp) {
    int idx = blockIdx.x * 256 + threadIdx.x;   // total 8*16*32*2*32*16 = 4,194,304
    int k = idx & 15;
    int t = idx >> 4;
    int op = t & 31; t >>= 5;
    int mt = t & 1;  t >>= 1;
    int u  = t & 31; t >>= 5;
    int vp = t & 15; t >>= 4;
    int g = t;
    int dv = k >> 3, cc = k & 7;
    int v = vp * 2 + dv;
    int o = mt * 32 + op;
    float f = (u < KS && v < KS)
                  ? w[(((size_t)o * CIN + g * CG + cc) * KS + u) * KS + v] : 0.0f;
    Wp[idx] = f2bf(f);
}

// Main conv, R5: 2m x 4n wave tile + B-register-rotation (vp-outer / u-inner).
// One block = 64 out-ch x 16x32 spatial tile for one batch image. 4 waves.
// Wave w owns output rows 4w..4w+3 (each row x 32 cols = one 32-wide n-tile).
// Key identity: B-frag(t,u) reads patch row (4w+t+u) -> frag(t,u) == frag(t+1,u-1).
// With u innermost, a 4-deep rotating register window F[] needs 1 ds_read/step
// (vs 4), and each A-frag feeds 8 MFMAs (vs 4) -> A global traffic halved.
// Ping-pong bank FN[] preloaded in the last 4 u-slots covers the vp column shift.
// VGPR: acc 2x4 f32x16 = 128 + ~100 arch -> 2 waves/SIMD; LDS 48 KB -> 2 blocks/CU.
__global__ __launch_bounds__(256, 2)
void conv_mfma_kernel(const short* __restrict__ P, const short* __restrict__ Wp,
                      const float* __restrict__ bias, float* __restrict__ out) {
    __shared__ __align__(16) short patch[PR * PC * CG];  // 49,152 B

    int bid = blockIdx.x;             // [0,1024)
    int b  = bid >> 7;
    int ty = (bid >> 3) & 15;
    int tx = bid & 7;
    int y0 = ty * TY, x0 = tx * TX;

    int tid  = threadIdx.x;
    int w    = tid >> 6;
    int lane = tid & 63;
    int n31  = lane & 31;             // spatial col within tile (MFMA n-index)
    int dv   = lane >> 5;             // k-half: v offset 0/1
    int w4   = w * 4;

    // A-frag lane offset within a 1024-elem (g,vp,u) block: o'=lane&31, k-base=dv*8
    const int a_off = n31 * 16 + dv * 8;
    // B lane column base (before vp shift): col = n31 + dv
    const int bcol = n31 + dv;

    f32x16 acc[2][4];                 // [m][t]
#pragma unroll
    for (int m = 0; m < 2; ++m)
#pragma unroll
        for (int t = 0; t < 4; ++t)
            acc[m][t] = (f32x16)(0.0f);

// One (vp) sweep: 32 u-steps. F = current column bank (rows rotate), FN = next-vp bank.
// Step u consumes a[u&3] (A) and F[(u+t)&3] (B, row 4w+t+u); then prefetches
// A step s+4 and B row 4w+u+4 into F[u&3] (u<=30); u=28..31 also preload FN[u-28].
#define VPBODY(VPv, F, FN)                                                        \
    {                                                                             \
        const int colb = (bcol + 2 * (VPv)) * CG;                                 \
        const int coln = (bcol + 2 * ((VPv) + 1)) * CG;                           \
        const int sbase = (VPv) * UPAD;                                           \
        _Pragma("unroll")                                                         \
        for (int uc = 0; uc < 8; ++uc) {                                          \
            _Pragma("unroll")                                                     \
            for (int d = 0; d < 4; ++d) {                                         \
                const int u = uc * 4 + d;                                         \
                _Pragma("unroll")                                                 \
                for (int m = 0; m < 2; ++m)                                       \
                    _Pragma("unroll")                                             \
                    for (int t = 0; t < 4; ++t)                                   \
                        acc[m][t] = __builtin_amdgcn_mfma_f32_32x32x16_bf16(      \
                            a[d][m], F[(u + t) & 3], acc[m][t], 0, 0, 0);         \
                {   /* A prefetch: step sbase+u+4 (linear; g-end overrun is into  \
                       allocated P region, data unused) */                        \
                    const short* Wn = Wa + (size_t)(sbase + u + 4) * 1024;        \
                    a[d][0] = *reinterpret_cast<const short8*>(Wn);               \
                    a[d][1] = *reinterpret_cast<const short8*>(Wn + 512);         \
                }                                                                 \
                if (u <= 30)                                                      \
                    F[u & 3] = *reinterpret_cast<const short8*>(                  \
                        patch + (w4 + u + 4) * (PC * CG) + colb);                 \
                if (u >= 28)                                                      \
                    FN[u - 28] = *reinterpret_cast<const short8*>(                \
                        patch + (w4 + (u - 28)) * (PC * CG) + coln);              \
            }                                                                     \
        }                                                                         \
    }

    for (int g = 0; g < NG; ++g) {
        __syncthreads();   // drain prev iter's LDS reads
        // ---- stage 48x64x8 bf16 patch via async global->LDS (16B per lane) ----
        const short* Pbase = P + (size_t)(b * NG + g) * PADDED * PADDED * CG;
#pragma unroll
        for (int it = 0; it < 12; ++it) {
            int t = it * 256 + tid;        // [0, 3072)
            int r  = t >> 6;
            int cl = t & 63;
            int sr = y0 + r;  if (sr > PADDED - 1) sr = PADDED - 1;   // slack rows:
            int sc = x0 + cl; if (sc > PADDED - 1) sc = PADDED - 1;   // clamp (junk ok)
            const short* gsrc = Pbase + ((size_t)sr * PADDED + sc) * CG;
            __builtin_amdgcn_global_load_lds(
                (const __attribute__((address_space(1))) void*)gsrc,
                (__attribute__((address_space(3))) void*)(patch + (size_t)t * CG),
                16, 0, 0);
        }
        __syncthreads();   // drains vmcnt(0): staging complete

        const short* Wa = Wp + (size_t)g * NSTEP * 1024 + a_off;

        short8 a[4][2], fA[4], fB[4];
        // A prologue: steps 0..3 into circular buffer
#pragma unroll
        for (int d = 0; d < 4; ++d) {
            a[d][0] = *reinterpret_cast<const short8*>(Wa + (size_t)d * 1024);
            a[d][1] = *reinterpret_cast<const short8*>(Wa + (size_t)d * 1024 + 512);
        }
        // initial B bank (vp=0): rows w4..w4+3 at col n31+dv
#pragma unroll
        for (int j = 0; j < 4; ++j)
            fA[j] = *reinterpret_cast<const short8*>(
                patch + (w4 + j) * (PC * CG) + bcol * CG);

        for (int vph = 0; vph < 8; ++vph) {
            VPBODY(2 * vph,     fA, fB)
            VPBODY(2 * vph + 1, fB, fA)
        }
    }
#undef VPBODY

    // ---- epilogue: C/D 32x32 layout: col(n)=lane&31 -> spatial x,
    //      row(o') = (r&3) + 8*(r>>2) + 4*dv; o = m*32 + o'
#pragma unroll
    for (int m = 0; m < 2; ++m) {
#pragma unroll
        for (int t = 0; t < 4; ++t) {
            int y = y0 + w4 + t;
#pragma unroll
            for (int r = 0; r < 16; ++r) {
                int o = m * 32 + (r & 3) + 8 * (r >> 2) + 4 * dv;
                out[(((size_t)b * COUT + o) * HW_ + y) * HW_ + x0 + n31] =
                    acc[m][t][r] + bias[o];
            }
        }
    }
}

extern "C" void kernel_launch(void* const* d_in, const int* in_sizes, int n_in,
                              void* d_out, int out_size, void* d_ws, size_t ws_size,
                              hipStream_t stream) {
    const float* sig  = (const float*)d_in[0];
    const float* wgt  = (const float*)d_in[1];
    const float* bias = (const float*)d_in[2];
    float* out = (float*)d_out;

    // ws layout: Wp (4,194,304 shorts = 8,388,608 B) then P (8*8*287*287*8 =
    // 42,172,928 shorts = 84,345,856 B). Total 92.73 MB (< previous 93.06 MB).
    short* Wp = (short*)d_ws;
    short* P  = (short*)d_ws + 4194304;

    pack_weight_kernel<<<16384, 256, 0, stream>>>(wgt, Wp);
    pad_input_kernel<<<20593, 256, 0, stream>>>(sig, P);
    conv_mfma_kernel<<<1024, 256, 0, stream>>>(P, Wp, bias, out);
}

// Round 5
// 3760.405 us; speedup vs baseline: 1.4480x; 1.4480x over previous
//
#include <hip/hip_runtime.h>
#include <hip/hip_bf16.h>
#include <stdint.h>

// Problem constants
#define B_    8
#define CIN   64
#define COUT  64
#define HW_   256
#define KS    31
#define PADDED 288   // padded spatial dim for P (pad offset 15, +2 slack)
#define CG    8      // channels per group
#define NG    8      // number of channel groups (CIN/CG)
#define TILE  16     // output spatial tile (both dims)
#define PATCH 48     // staged patch rows/cols (16+31-1=46 real, padded to 48)
#define VP    16     // v-pair count: v = vp*2+dv, dv in {0,1}; v==31 zero-padded
#define NSTEP (KS * VP)  // 496 K-steps of K=16 per channel-group

typedef __attribute__((ext_vector_type(8))) short short8;
typedef __attribute__((ext_vector_type(16))) float f32x16;

__device__ __forceinline__ short f2bf(float f) {
    __hip_bfloat16 h = __float2bfloat16(f);
    return __builtin_bit_cast(short, h);
}

// P layout: [b][g][y'][x'][cc] bf16, y',x' in [0,288), value = signal[b][g*8+cc][y'-15][x'-15] or 0
__global__ void pad_input_kernel(const float* __restrict__ sig, short* __restrict__ P) {
    int idx = blockIdx.x * 256 + threadIdx.x;   // total 8*8*288*288 = 5,308,416
    int x = idx % PADDED;
    int t = idx / PADDED;
    int y = t % PADDED;
    t /= PADDED;
    int g = t % NG;
    int b = t / NG;
    int ys = y - 15, xs = x - 15;
    bool in = (ys >= 0 && ys < HW_ && xs >= 0 && xs < HW_);
    const float* sp = sig + (((size_t)(b*CIN + g*CG) * HW_ + ys) * HW_ + xs);
    short8 v;
#pragma unroll
    for (int cc = 0; cc < CG; ++cc) {
        float f = in ? sp[(size_t)cc * HW_ * HW_] : 0.0f;
        v[cc] = f2bf(f);
    }
    *reinterpret_cast<short8*>(P + (size_t)idx * CG) = v;
}

// Wp layout (32x32x16 MFMA): [g][u][vp][mt(2)][o'(32)][k(16)]
// k = dv*8 + cc, v = vp*2 + dv (v==31 zero-padded), o = mt*32 + o'
// A-frag lane mapping: row(o') = lane&31, k-base = (lane>>5)*8, 8 contiguous shorts (16 B)
// NOTE: contiguous in step order s = u*16+vp -> A prefetch address is Wg + s*1024.
__global__ void pack_weight_kernel(const float* __restrict__ w, short* __restrict__ Wp) {
    int idx = blockIdx.x * 256 + threadIdx.x;   // total 8*31*16*1024 = 4,063,232
    int k = idx & 15;
    int t = idx >> 4;
    int op = t & 31; t >>= 5;
    int mt = t & 1;  t >>= 1;
    int vp = t & 15; t >>= 4;
    int u = t % KS;
    int g = t / KS;
    int dv = k >> 3, cc = k & 7;
    int v = vp * 2 + dv;
    int o = mt * 32 + op;
    float f = (v < KS) ? w[(((size_t)o * CIN + g * CG + cc) * KS + u) * KS + v] : 0.0f;
    Wp[idx] = f2bf(f);
}

// Main conv, R6 (resubmit after infra failure): R4 structure (32x32x16 MFMA,
// depth-4 A / depth-2 B register pipeline) at 4 blocks/CU.
// R5 post-mortem: stall/step ~= L3 latency (~590cyc) on the A sweep (Wp 8.4MB
// thrashes the 4MiB XCD L2); MFMA blocks its wave, so cover comes from OTHER
// resident waves. R5 cut occupancy 3->2 blocks/CU and regressed; R6 raises it
// to 4 (64 arch VGPR + 64 acc AGPR = 128 unified = 4 waves/SIMD boundary;
// LDS 36,864*4 = 147KB <= 160KB). Stall tolerance/wave doubles to ~512cyc.
__global__ __launch_bounds__(256, 4)
void conv_mfma_kernel(const short* __restrict__ P, const short* __restrict__ Wp,
                      const float* __restrict__ bias, float* __restrict__ out) {
    __shared__ __align__(16) short patch[PATCH * PATCH * CG];  // 36,864 B

    int bid = blockIdx.x;             // [0,2048)
    int b  = bid >> 8;
    int ty = (bid >> 4) & 15;
    int tx = bid & 15;
    int y0 = ty * TILE, x0 = tx * TILE;

    int tid  = threadIdx.x;
    int w    = tid >> 6;
    int lane = tid & 63;
    int x15  = lane & 15;
    int rs   = (lane >> 4) & 1;       // row-sub within n-tile (n>>4)
    int dv   = lane >> 5;             // k-half: v offset 0/1

    // A-frag lane offset within a 1024-elem (g,u,vp) block: o'=lane&31, k-base=dv*8
    const int a_off = (lane & 31) * 16 + dv * 8;

    // B-frag LDS element offsets (t = n-tile 0/1): row = 4w + 2t + rs, col = x15 + dv
    int boff[2];
#pragma unroll
    for (int t = 0; t < 2; ++t)
        boff[t] = ((w * 4 + t * 2 + rs) * PATCH + x15 + dv) * CG;

    f32x16 acc[2][2];
#pragma unroll
    for (int m = 0; m < 2; ++m)
#pragma unroll
        for (int t = 0; t < 2; ++t)
            acc[m][t] = (f32x16)(0.0f);

    for (int g = 0; g < NG; ++g) {
        __syncthreads();   // protect previous iteration's LDS reads
        // ---- stage 48x48x8 bf16 patch via async global->LDS (16B per lane) ----
        const short* Pbase = P + (size_t)(b * NG + g) * PADDED * PADDED * CG;
#pragma unroll
        for (int it = 0; it < 9; ++it) {
            int t = it * 256 + tid;        // [0, 2304)
            int r  = t / PATCH;
            int cl = t - r * PATCH;
            const short* gsrc = Pbase + ((size_t)(y0 + r) * PADDED + (x0 + cl)) * CG;
            __builtin_amdgcn_global_load_lds(
                (const __attribute__((address_space(1))) void*)gsrc,
                (__attribute__((address_space(3))) void*)(patch + (size_t)t * CG),
                16, 0, 0);
        }
        __syncthreads();   // drains vmcnt(0): staging complete

        const short* Wg = Wp + (size_t)g * NSTEP * 1024;
        const short* Wa = Wg + a_off;      // per-lane A base; step s block at +s*1024

        // ---- K loop: 496 steps (31 u-taps x 16 v-pairs), K=16 per step ----
        // circular prefetch: a[s%4] holds A of step s; bf[s%2] holds B of step s.
        short8 a[4][2], bf[2][2];
#pragma unroll
        for (int d = 0; d < 4; ++d) {
            a[d][0] = *reinterpret_cast<const short8*>(Wa + (size_t)d * 1024);
            a[d][1] = *reinterpret_cast<const short8*>(Wa + (size_t)d * 1024 + 512);
        }
#pragma unroll
        for (int d = 0; d < 2; ++d) {
            // step d: u=0, vp=d -> offset vp*2*CG = d*16 elements
            bf[d][0] = *reinterpret_cast<const short8*>(patch + boff[0] + d * 16);
            bf[d][1] = *reinterpret_cast<const short8*>(patch + boff[1] + d * 16);
        }

        for (int kk = 0; kk < NSTEP; kk += 4) {
#pragma unroll
            for (int d = 0; d < 4; ++d) {
                int s = kk + d;
                // consume a[d] (=a[s%4]) and bf[d&1] (=bf[s%2])
#pragma unroll
                for (int m = 0; m < 2; ++m)
#pragma unroll
                    for (int t = 0; t < 2; ++t)
                        acc[m][t] = __builtin_amdgcn_mfma_f32_32x32x16_bf16(
                            a[d][m], bf[d & 1][t], acc[m][t], 0, 0, 0);
                // prefetch A for step s+4 into a[d]. Unconditional: at s+4>495 this
                // reads past Wg into following workspace (allocated; data unused).
                {
                    const short* Wn = Wa + (size_t)(s + 4) * 1024;
                    a[d][0] = *reinterpret_cast<const short8*>(Wn);
                    a[d][1] = *reinterpret_cast<const short8*>(Wn + 512);
                }
                // prefetch B for step s+2 into bf[d&1]. At s+2>495 reads the PATCH=48
                // slack rows/cols (max elem 17,816 < 18,432) -- in-bounds, unused.
                {
                    int sp = s + 2;
                    int off = (sp >> 4) * (PATCH * CG) + (sp & 15) * (2 * CG);
                    bf[d & 1][0] = *reinterpret_cast<const short8*>(patch + boff[0] + off);
                    bf[d & 1][1] = *reinterpret_cast<const short8*>(patch + boff[1] + off);
                }
            }
        }
    }

    // ---- epilogue: C/D 32x32 layout: col=lane&31 (n = rs*16+x15),
    //      row = (r&3) + 8*(r>>2) + 4*dv  (o within the 32-o m-tile)
#pragma unroll
    for (int m = 0; m < 2; ++m) {
#pragma unroll
        for (int t = 0; t < 2; ++t) {
            int y = y0 + w * 4 + t * 2 + rs;
#pragma unroll
            for (int r = 0; r < 16; ++r) {
                int o = m * 32 + (r & 3) + 8 * (r >> 2) + 4 * dv;
                out[(((size_t)b * COUT + o) * HW_ + y) * HW_ + x0 + x15] =
                    acc[m][t][r] + bias[o];
            }
        }
    }
}

extern "C" void kernel_launch(void* const* d_in, const int* in_sizes, int n_in,
                              void* d_out, int out_size, void* d_ws, size_t ws_size,
                              hipStream_t stream) {
    const float* sig  = (const float*)d_in[0];
    const float* wgt  = (const float*)d_in[1];
    const float* bias = (const float*)d_in[2];
    float* out = (float*)d_out;

    // ws layout: Wp (4,063,232 shorts = 8,126,464 B) then P (42,467,328 shorts = 84,934,656 B)
    short* Wp = (short*)d_ws;
    short* P  = (short*)d_ws + 4063232;

    pack_weight_kernel<<<15872, 256, 0, stream>>>(wgt, Wp);
    pad_input_kernel<<<20736, 256, 0, stream>>>(sig, P);
    conv_mfma_kernel<<<2048, 256, 0, stream>>>(P, Wp, bias, out);
}

// Round 6
// 3234.848 us; speedup vs baseline: 1.6832x; 1.1625x over previous
//
#include <hip/hip_runtime.h>
#include <hip/hip_bf16.h>
#include <stdint.h>

// Problem constants
#define B_    8
#define CIN   64
#define COUT  64
#define HW_   256
#define KS    31
#define PADDED 288   // padded spatial dim for P (pad offset 15, +2 slack)
#define CG    8      // channels per group
#define NG    8      // number of channel groups (CIN/CG)
#define TILE  16     // output spatial tile (both dims)
#define PATCH 48     // staged patch rows/cols (16+31-1=46 real, padded to 48)
#define VP    16     // v-pair count: v = vp*2+dv, dv in {0,1}; v==31 zero-padded
#define NSTEP (KS * VP)   // 496 K-steps of K=16 per channel-group
#define CHUNK 4           // K-steps per LDS ring buffer
#define NCHUNK (NSTEP / CHUNK)  // 124 chunks per channel-group

typedef __attribute__((ext_vector_type(8))) short short8;
typedef __attribute__((ext_vector_type(16))) float f32x16;

#define AS1 __attribute__((address_space(1)))
#define AS3 __attribute__((address_space(3)))

__device__ __forceinline__ short f2bf(float f) {
    __hip_bfloat16 h = __float2bfloat16(f);
    return __builtin_bit_cast(short, h);
}

// P layout: [b][g][y'][x'][cc] bf16, y',x' in [0,288), value = signal[b][g*8+cc][y'-15][x'-15] or 0
__global__ void pad_input_kernel(const float* __restrict__ sig, short* __restrict__ P) {
    int idx = blockIdx.x * 256 + threadIdx.x;   // total 8*8*288*288 = 5,308,416
    int x = idx % PADDED;
    int t = idx / PADDED;
    int y = t % PADDED;
    t /= PADDED;
    int g = t % NG;
    int b = t / NG;
    int ys = y - 15, xs = x - 15;
    bool in = (ys >= 0 && ys < HW_ && xs >= 0 && xs < HW_);
    const float* sp = sig + (((size_t)(b*CIN + g*CG) * HW_ + ys) * HW_ + xs);
    short8 v;
#pragma unroll
    for (int cc = 0; cc < CG; ++cc) {
        float f = in ? sp[(size_t)cc * HW_ * HW_] : 0.0f;
        v[cc] = f2bf(f);
    }
    *reinterpret_cast<short8*>(P + (size_t)idx * CG) = v;
}

// Wp layout (R7, lane-major for LDS staging): [g][s(496)][mt(2)][lane(64)][j(8)]
// Step s = u*16 + vp. Lane l holds A[o' = l&31][k = (l>>5)*8 + j], where
// k = dv*8 + cc -> dv = l>>5, cc = j, v = vp*2 + dv (v==31 zero-padded).
// Staging is linear (global_load_lds 16B/lane); ds_read is ring + lane*16 (conflict-free).
__global__ void pack_weight_kernel(const float* __restrict__ w, short* __restrict__ Wp) {
    int idx = blockIdx.x * 256 + threadIdx.x;   // total 8*496*1024 = 4,063,232
    int j    = idx & 7;
    int lane = (idx >> 3) & 63;
    int mt   = (idx >> 9) & 1;
    int blk  = idx >> 10;          // [0, 3968)
    int s    = blk % NSTEP;
    int g    = blk / NSTEP;
    int op = lane & 31;
    int dv = lane >> 5;
    int u  = s >> 4;
    int vp = s & 15;
    int v  = vp * 2 + dv;
    int o  = mt * 32 + op;
    float f = (v < KS) ? w[(((size_t)o * CIN + g * CG + j) * KS + u) * KS + v] : 0.0f;
    Wp[idx] = f2bf(f);
}

// Main conv, R7: A-stream through a shared LDS ring (T3-minimum 2-phase).
// R6 post-mortem: ~900cyc stall per K-step per wave despite depth-4 register
// prefetch -> either per-step waitcnt serialization or 4x-redundant A loads
// saturating L1 (~64 B/cyc demand). Fix: block stages each 4-step A chunk ONCE
// into an LDS ring (global_load_lds, traffic /4); single vmcnt(0)+barrier per
// chunk (stage issued a full compute phase earlier -> cheap drain); A ds_reads
// lane-major contiguous (2 lanes/bank = free). LDS 36,864+16,384 = 53,248 B
// -> 3 blocks/CU (159,744 <= 163,840). acc 64 AGPR + ~70 arch VGPR.
__global__ __launch_bounds__(256, 3)
void conv_mfma_kernel(const short* __restrict__ P, const short* __restrict__ Wp,
                      const float* __restrict__ bias, float* __restrict__ out) {
    __shared__ __align__(16) short patch[PATCH * PATCH * CG];  // 36,864 B
    __shared__ __align__(16) short ringA[2 * CHUNK * 1024];    // 16,384 B

    int bid = blockIdx.x;             // [0,2048)
    int b  = bid >> 8;
    int ty = (bid >> 4) & 15;
    int tx = bid & 15;
    int y0 = ty * TILE, x0 = tx * TILE;

    int tid  = threadIdx.x;
    int w    = tid >> 6;
    int lane = tid & 63;
    int x15  = lane & 15;
    int rs   = (lane >> 4) & 1;       // row-sub within n-tile (n>>4)
    int dv   = lane >> 5;             // k-half: v offset 0/1

    // B-frag LDS element offsets (t = n-tile 0/1): row = 4w + 2t + rs, col = x15 + dv
    int boff[2];
#pragma unroll
    for (int t = 0; t < 2; ++t)
        boff[t] = ((w * 4 + t * 2 + rs) * PATCH + x15 + dv) * CG;

    f32x16 acc[2][2];
#pragma unroll
    for (int m = 0; m < 2; ++m)
#pragma unroll
        for (int t = 0; t < 2; ++t)
            acc[m][t] = (f32x16)(0.0f);

    for (int g = 0; g < NG; ++g) {
        // (end-of-previous-chunk barrier already synced all LDS readers)
        // ---- stage 48x48x8 patch + A chunk 0 via async global->LDS ----
        const short* Pbase = P + (size_t)(b * NG + g) * PADDED * PADDED * CG;
#pragma unroll
        for (int it = 0; it < 9; ++it) {
            int t = it * 256 + tid;        // [0, 2304)
            int r  = t / PATCH;
            int cl = t - r * PATCH;
            const short* gsrc = Pbase + ((size_t)(y0 + r) * PADDED + (x0 + cl)) * CG;
            __builtin_amdgcn_global_load_lds(
                (const AS1 void*)gsrc, (AS3 void*)(patch + (size_t)t * CG), 16, 0, 0);
        }
        const short* Wg = Wp + (size_t)g * NSTEP * 1024;   // this g's weight slice
        // chunk 0 -> ringA[0..4095] (8,192 B, 2 x 16B per thread, linear)
        __builtin_amdgcn_global_load_lds(
            (const AS1 void*)(Wg + tid * 8), (AS3 void*)(ringA + tid * 8), 16, 0, 0);
        __builtin_amdgcn_global_load_lds(
            (const AS1 void*)(Wg + 2048 + tid * 8), (AS3 void*)(ringA + 2048 + tid * 8),
            16, 0, 0);
        __syncthreads();   // drains vmcnt(0): patch + chunk 0 staged

        // ---- B prologue: steps 0,1 into ping-pong regs ----
        short8 a[2][2], bf[2][2];
#pragma unroll
        for (int d = 0; d < 2; ++d) {
            bf[d][0] = *reinterpret_cast<const short8*>(patch + boff[0] + d * 16);
            bf[d][1] = *reinterpret_cast<const short8*>(patch + boff[1] + d * 16);
        }

        // ---- chunk loop: 124 chunks x 4 K-steps ----
        for (int c = 0; c < NCHUNK; ++c) {
            // stage chunk c+1 into the other ring buffer (skipped on last chunk)
            if (c + 1 < NCHUNK) {
                const short* gs = Wg + (size_t)(c + 1) * (CHUNK * 1024);
                short* stg = ringA + ((c & 1) ^ 1) * (CHUNK * 1024);
                __builtin_amdgcn_global_load_lds(
                    (const AS1 void*)(gs + tid * 8), (AS3 void*)(stg + tid * 8), 16, 0, 0);
                __builtin_amdgcn_global_load_lds(
                    (const AS1 void*)(gs + 2048 + tid * 8),
                    (AS3 void*)(stg + 2048 + tid * 8), 16, 0, 0);
            }
            // per-lane A base in current ring buffer (staged during chunk c-1)
            const short* Ab = ringA + (c & 1) * (CHUNK * 1024) + lane * 8;
            // A prologue: step 0 of chunk (st-block = 1024 shorts, mt-block = 512)
            a[0][0] = *reinterpret_cast<const short8*>(Ab);
            a[0][1] = *reinterpret_cast<const short8*>(Ab + 512);
#pragma unroll
            for (int st = 0; st < CHUNK; ++st) {
                int pb = st & 1;
                if (st + 1 < CHUNK) {
                    a[pb ^ 1][0] = *reinterpret_cast<const short8*>(Ab + (st + 1) * 1024);
                    a[pb ^ 1][1] = *reinterpret_cast<const short8*>(Ab + (st + 1) * 1024 + 512);
                }
#pragma unroll
                for (int m = 0; m < 2; ++m)
#pragma unroll
                    for (int t = 0; t < 2; ++t)
                        acc[m][t] = __builtin_amdgcn_mfma_f32_32x32x16_bf16(
                            a[pb][m], bf[st & 1][t], acc[m][t], 0, 0, 0);
                // B prefetch for step s+2 into the just-consumed slot.
                // At g end (s+2 up to 497) reads PATCH slack: max elem 17,816 < 18,432.
                {
                    int sp = c * CHUNK + st + 2;
                    int off = (sp >> 4) * (PATCH * CG) + (sp & 15) * (2 * CG);
                    bf[st & 1][0] = *reinterpret_cast<const short8*>(patch + boff[0] + off);
                    bf[st & 1][1] = *reinterpret_cast<const short8*>(patch + boff[1] + off);
                }
            }
            // one barrier per chunk: (i) compiler drains vmcnt(0) -> chunk c+1 staged;
            // (ii) all waves done reading ring[c&1] before chunk c+1 overwrites it.
            __syncthreads();
        }
    }

    // ---- epilogue: C/D 32x32 layout: col=lane&31 (n = rs*16+x15),
    //      row = (r&3) + 8*(r>>2) + 4*dv  (o within the 32-o m-tile)
#pragma unroll
    for (int m = 0; m < 2; ++m) {
#pragma unroll
        for (int t = 0; t < 2; ++t) {
            int y = y0 + w * 4 + t * 2 + rs;
#pragma unroll
            for (int r = 0; r < 16; ++r) {
                int o = m * 32 + (r & 3) + 8 * (r >> 2) + 4 * dv;
                out[(((size_t)b * COUT + o) * HW_ + y) * HW_ + x0 + x15] =
                    acc[m][t][r] + bias[o];
            }
        }
    }
}

extern "C" void kernel_launch(void* const* d_in, const int* in_sizes, int n_in,
                              void* d_out, int out_size, void* d_ws, size_t ws_size,
                              hipStream_t stream) {
    const float* sig  = (const float*)d_in[0];
    const float* wgt  = (const float*)d_in[1];
    const float* bias = (const float*)d_in[2];
    float* out = (float*)d_out;

    // ws layout: Wp (4,063,232 shorts = 8,126,464 B) then P (42,467,328 shorts = 84,934,656 B)
    short* Wp = (short*)d_ws;
    short* P  = (short*)d_ws + 4063232;

    pack_weight_kernel<<<15872, 256, 0, stream>>>(wgt, Wp);
    pad_input_kernel<<<20736, 256, 0, stream>>>(sig, P);
    conv_mfma_kernel<<<2048, 256, 0, stream>>>(P, Wp, bias, out);
}

// Round 7
// 3053.588 us; speedup vs baseline: 1.7832x; 1.0594x over previous
//
#include <hip/hip_runtime.h>
#include <hip/hip_bf16.h>
#include <stdint.h>

// Problem constants
#define B_    8
#define CIN   64
#define COUT  64
#define HW_   256
#define KS    31
#define PADDED 287   // padded spatial dim for P (pad offset 15): idx = coord+15, in [0,287)
#define CG    8      // channels per group
#define NG    8      // number of channel groups (CIN/CG)
#define TY    16     // output tile rows per block
#define TX    32     // output tile cols per block
#define PR    48     // staged patch rows (16+31-1=46 real, +2 slack)
#define PC    64     // staged patch cols (32+31-1=62 real, +2 slack)
#define UPAD  32     // u-taps padded 31->32 (u=31 weights zero)
#define VP    16     // v-pair count: v = vp*2+dv, dv in {0,1}; v==31 zero-padded
#define NSTEP (VP * UPAD)   // 512 K-steps of K=16 per channel-group
#define CHUNK 4             // K-steps per ring buffer (= 4096 shorts)
#define RB    (CHUNK * 1024)

typedef __attribute__((ext_vector_type(8))) short short8;
typedef __attribute__((ext_vector_type(16))) float f32x16;

#define AS1 __attribute__((address_space(1)))
#define AS3 __attribute__((address_space(3)))

__device__ __forceinline__ short f2bf(float f) {
    __hip_bfloat16 h = __float2bfloat16(f);
    return __builtin_bit_cast(short, h);
}

// P layout: [b][g][y'][x'][cc] bf16, y',x' in [0,287), value = signal[b][g*8+cc][y'-15][x'-15] or 0
__global__ void pad_input_kernel(const float* __restrict__ sig, short* __restrict__ P) {
    int idx = blockIdx.x * 256 + threadIdx.x;   // total 8*8*287*287 = 5,271,616
    if (idx >= B_ * NG * PADDED * PADDED) return;
    int x = idx % PADDED;
    int t = idx / PADDED;
    int y = t % PADDED;
    t /= PADDED;
    int g = t % NG;
    int b = t / NG;
    int ys = y - 15, xs = x - 15;
    bool in = (ys >= 0 && ys < HW_ && xs >= 0 && xs < HW_);
    const float* sp = sig + (((size_t)(b*CIN + g*CG) * HW_ + ys) * HW_ + xs);
    short8 v;
#pragma unroll
    for (int cc = 0; cc < CG; ++cc) {
        float f = in ? sp[(size_t)cc * HW_ * HW_] : 0.0f;
        v[cc] = f2bf(f);
    }
    *reinterpret_cast<short8*>(P + (size_t)idx * CG) = v;
}

// Wp layout (u-INNER for B-rotation): [g][s(512)][mt(2)][lane(64)][j(8)]
// s = vp*32 + u (u innermost). Lane l: o' = l&31, k = (l>>5)*8 + j;
// dv = l>>5, v = vp*2+dv (v==31 zero-pad), u==31 zero-pad, o = mt*32 + o'.
// Staging linear (global_load_lds); ds_read = ring + lane*16B (2 lanes/bank, free).
__global__ void pack_weight_kernel(const float* __restrict__ w, short* __restrict__ Wp) {
    int idx = blockIdx.x * 256 + threadIdx.x;   // total 8*512*1024 = 4,194,304
    int j    = idx & 7;
    int lane = (idx >> 3) & 63;
    int mt   = (idx >> 9) & 1;
    int s    = (idx >> 10) & 511;
    int g    = idx >> 19;
    int op = lane & 31;
    int dv = lane >> 5;
    int u  = s & 31;
    int vp = s >> 5;
    int v  = vp * 2 + dv;
    int o  = mt * 32 + op;
    float f = (u < KS && v < KS)
                  ? w[(((size_t)o * CIN + g * CG + j) * KS + u) * KS + v] : 0.0f;
    Wp[idx] = f2bf(f);
}

// Main conv, R8: R7 LDS A-ring + R5 B-row-rotation, 16x32 tile, 2m x 4t waves.
// R7 post-mortem: LDS read BW bound (~1 KB/MFMA: A 4x-redundant across waves +
// 2 B reads per 4 MFMA; ~1880 cyc LDS service vs 1292 cyc MFMA window per CU).
// Fix: per-wave reuse. Wave w owns rows 4w..4w+3 x 32 cols; u-inner order makes
// B-frag(t,u) == B-frag(t+1,u-1) -> rolling 4-reg window, 1 B read/step; each
// A-frag feeds 8 MFMAs. LDS/MFMA: 1.0 -> 0.45 KB. A stays in the proven ring
// (stage once/block, chunk barrier). acc 128 AGPR + ~100 arch -> 2 waves/SIMD;
// LDS 49,152 + 16,384 = 65,536 -> 2 blocks/CU.
__global__ __launch_bounds__(256, 2)
void conv_mfma_kernel(const short* __restrict__ P, const short* __restrict__ Wp,
                      const float* __restrict__ bias, float* __restrict__ out) {
    __shared__ __align__(16) short patch[PR * PC * CG];  // 49,152 B
    __shared__ __align__(16) short ringA[2 * RB];        // 16,384 B

    int bid = blockIdx.x;             // [0,1024)
    int b  = bid >> 7;
    int ty = (bid >> 3) & 15;
    int tx = bid & 7;
    int y0 = ty * TY, x0 = tx * TX;

    int tid  = threadIdx.x;
    int w    = tid >> 6;
    int lane = tid & 63;
    int n31  = lane & 31;             // spatial col within tile (MFMA n-index)
    int dv   = lane >> 5;             // k-half: v offset 0/1
    int w4   = w * 4;

    const int bcol = n31 + dv;        // B lane col base (before vp shift)

    f32x16 acc[2][4];                 // [m][t]
#pragma unroll
    for (int m = 0; m < 2; ++m)
#pragma unroll
        for (int t = 0; t < 4; ++t)
            acc[m][t] = (f32x16)(0.0f);

// One vp sweep = 8 chunks x 4 u-steps. F = current col bank (rows rotate),
// FN = next-vp bank (preloaded at u=28..31). Ring chunk c = VPv*8+uc; parity
// uc&1 (vp*8 even). Stage chunk c+1 at top; one barrier per chunk.
#define VPBODY(VPv, F, FN)                                                        \
    {                                                                             \
        const int colb = (bcol + 2 * (VPv)) * CG;                                 \
        const int coln = (bcol + 2 * ((VPv) + 1)) * CG;                           \
        _Pragma("unroll")                                                         \
        for (int uc = 0; uc < 8; ++uc) {                                          \
            {   /* stage ring chunk (VPv*8+uc+1); overrun at g end reads next    \
                   g's chunk 0 (identical to its explicit restage) or P region */ \
                const short* gs = WgA + (size_t)((VPv) * 8 + uc + 1) * RB;        \
                short* stg = ringA + ((uc + 1) & 1) * RB;                         \
                __builtin_amdgcn_global_load_lds(                                 \
                    (const AS1 void*)(gs + tid * 8),                              \
                    (AS3 void*)(stg + tid * 8), 16, 0, 0);                        \
                __builtin_amdgcn_global_load_lds(                                 \
                    (const AS1 void*)(gs + 2048 + tid * 8),                       \
                    (AS3 void*)(stg + 2048 + tid * 8), 16, 0, 0);                 \
            }                                                                     \
            const short* Ab = ringA + (uc & 1) * RB + lane * 8;                   \
            short8 aa[2][2];                                                      \
            aa[0][0] = *reinterpret_cast<const short8*>(Ab);                      \
            aa[0][1] = *reinterpret_cast<const short8*>(Ab + 512);                \
            _Pragma("unroll")                                                     \
            for (int d = 0; d < 4; ++d) {                                         \
                const int u = uc * 4 + d;                                         \
                const int pb = d & 1;                                             \
                if (d < 3) {                                                      \
                    aa[pb ^ 1][0] = *reinterpret_cast<const short8*>(             \
                        Ab + (d + 1) * 1024);                                     \
                    aa[pb ^ 1][1] = *reinterpret_cast<const short8*>(             \
                        Ab + (d + 1) * 1024 + 512);                               \
                }                                                                 \
                _Pragma("unroll")                                                 \
                for (int m = 0; m < 2; ++m)                                       \
                    _Pragma("unroll")                                             \
                    for (int t = 0; t < 4; ++t)                                   \
                        acc[m][t] = __builtin_amdgcn_mfma_f32_32x32x16_bf16(      \
                            aa[pb][m], F[(u + t) & 3], acc[m][t], 0, 0, 0);       \
                if (u <= 30)                                                      \
                    F[u & 3] = *reinterpret_cast<const short8*>(                  \
                        patch + (w4 + u + 4) * (PC * CG) + colb);                 \
                if (u >= 28)                                                      \
                    FN[u - 28] = *reinterpret_cast<const short8*>(                \
                        patch + (w4 + (u - 28)) * (PC * CG) + coln);              \
            }                                                                     \
            __syncthreads(); /* drains vmcnt(0): chunk c+1 staged; ring reads done */ \
        }                                                                         \
    }

    for (int g = 0; g < NG; ++g) {
        // (final barrier of previous g synced all LDS readers)
        // ---- stage 48x64 patch (clamped) + ring chunk 0 ----
        const short* Pbase = P + (size_t)(b * NG + g) * PADDED * PADDED * CG;
#pragma unroll
        for (int it = 0; it < 12; ++it) {
            int t = it * 256 + tid;        // [0, 3072)
            int r  = t >> 6;
            int cl = t & 63;
            int sr = y0 + r;  if (sr > PADDED - 1) sr = PADDED - 1;  // slack clamp
            int sc = x0 + cl; if (sc > PADDED - 1) sc = PADDED - 1;  // (junk unused)
            const short* gsrc = Pbase + ((size_t)sr * PADDED + sc) * CG;
            __builtin_amdgcn_global_load_lds(
                (const AS1 void*)gsrc, (AS3 void*)(patch + (size_t)t * CG), 16, 0, 0);
        }
        const short* WgA = Wp + (size_t)g * NSTEP * 1024;
        __builtin_amdgcn_global_load_lds(
            (const AS1 void*)(WgA + tid * 8), (AS3 void*)(ringA + tid * 8), 16, 0, 0);
        __builtin_amdgcn_global_load_lds(
            (const AS1 void*)(WgA + 2048 + tid * 8),
            (AS3 void*)(ringA + 2048 + tid * 8), 16, 0, 0);
        __syncthreads();   // drains vmcnt(0): patch + chunk 0 staged

        short8 fA[4], fB[4];
        // initial B bank (vp=0): rows w4..w4+3 at col bcol
#pragma unroll
        for (int j = 0; j < 4; ++j)
            fA[j] = *reinterpret_cast<const short8*>(
                patch + (w4 + j) * (PC * CG) + bcol * CG);

        for (int vph = 0; vph < 8; ++vph) {
            VPBODY(2 * vph,     fA, fB)
            VPBODY(2 * vph + 1, fB, fA)
        }
    }
#undef VPBODY

    // ---- epilogue: C/D 32x32 layout: col(n)=lane&31 -> spatial x,
    //      row(o') = (r&3) + 8*(r>>2) + 4*dv; o = m*32 + o'
#pragma unroll
    for (int m = 0; m < 2; ++m) {
#pragma unroll
        for (int t = 0; t < 4; ++t) {
            int y = y0 + w4 + t;
#pragma unroll
            for (int r = 0; r < 16; ++r) {
                int o = m * 32 + (r & 3) + 8 * (r >> 2) + 4 * dv;
                out[(((size_t)b * COUT + o) * HW_ + y) * HW_ + x0 + n31] =
                    acc[m][t][r] + bias[o];
            }
        }
    }
}

extern "C" void kernel_launch(void* const* d_in, const int* in_sizes, int n_in,
                              void* d_out, int out_size, void* d_ws, size_t ws_size,
                              hipStream_t stream) {
    const float* sig  = (const float*)d_in[0];
    const float* wgt  = (const float*)d_in[1];
    const float* bias = (const float*)d_in[2];
    float* out = (float*)d_out;

    // ws layout: Wp (4,194,304 shorts = 8,388,608 B) then P (8*8*287*287*8 =
    // 42,172,928 shorts = 84,345,856 B). Total 92.73 MB (proven R5 footprint).
    short* Wp = (short*)d_ws;
    short* P  = (short*)d_ws + 4194304;

    pack_weight_kernel<<<16384, 256, 0, stream>>>(wgt, Wp);
    pad_input_kernel<<<20593, 256, 0, stream>>>(sig, P);
    conv_mfma_kernel<<<1024, 256, 0, stream>>>(P, Wp, bias, out);
}